// Round 2
// baseline (213.035 us; speedup 1.0000x reference)
//
#include <hip/hip_runtime.h>

// B=4, DIN=DM=256, N=256, L=64, H=4, LH=16.
// Block = (b, n, head-pair): grid = 4*256*2 = 2048 blocks, 512 threads (8 waves).
// Per block: l-window of 32 (2 heads x 16). LDS 66KB -> 2 blocks/CU.
// Online-softmax attention (one 32x32 S-tile live) -> ~90 VGPR -> 4+ waves/SIMD.
// All MFMA fragment index math carried over from the verified round-1 kernel.

typedef unsigned int u32;
typedef unsigned short u16;
typedef __attribute__((ext_vector_type(8))) short s8v;    // 8 x bf16
typedef __attribute__((ext_vector_type(16))) float f16v;  // 16 x f32 acc

// LDS regions (u16 indices). XS also serves as ATT after projections.
#define XS 0        // X^T blocked: [cblk 0..31][l 0..31][j 0..7]  (8192)
#define QT 8192     // q^T blocked: [lblk 0..3][d 0..255][j 0..7]  (8192)
#define KT 16384    // k^T blocked: same                            (8192)
#define VT 24576    // v   blocked: [eblk 0..31][l 0..31][j 0..7]  (8192)
#define LDS_TOT 33792  // + 1024 pad for staging overlay (67.5 KB)
#define LSTR 36     // linear staging row stride in u16 (72B, 8B-aligned)

__device__ __forceinline__ u16 f2bf(float x) {
  union { float f; u32 u; } c; c.f = x;
  return (u16)((c.u + 0x7FFFu + ((c.u >> 16) & 1u)) >> 16);  // RNE
}
__device__ __forceinline__ u32 pk2(float a, float b) {
  return (u32)f2bf(a) | ((u32)f2bf(b) << 16);
}

__global__ void cvt_weights(const float* __restrict__ wq, const float* __restrict__ wk,
                            const float* __restrict__ wv, const float* __restrict__ wo,
                            u16* __restrict__ out) {
  int i = blockIdx.x * 256 + threadIdx.x;  // 0..65535
  out[i]          = f2bf(wq[i]);
  out[i + 65536]  = f2bf(wk[i]);
  out[i + 131072] = f2bf(wv[i]);
  out[i + 196608] = f2bf(wo[i]);
}

// global fp32 X[c][l-window 32] -> linear bf16 lds[linoff + c*LSTR + l]
__device__ __forceinline__ void stage_lin(const float* __restrict__ src, u16* lds,
                                          int linoff, int tid) {
#pragma unroll
  for (int it = 0; it < 4; ++it) {
    int f4 = it * 512 + tid;           // 0..2047 float4s (256 c x 8 per row)
    int c = f4 >> 3;
    int l4 = (f4 & 7) << 2;
    const float4 v = *reinterpret_cast<const float4*>(src + c * 16384 + l4);
    uint2 w; w.x = pk2(v.x, v.y); w.y = pk2(v.z, v.w);
    *reinterpret_cast<uint2*>(&lds[linoff + c * LSTR + l4]) = w;
  }
}

// linear lds[c][l] -> blocked XS[cblk][l][j]
__device__ __forceinline__ void lin_to_xs(u16* lds, int linoff, int tid) {
#pragma unroll
  for (int it = 0; it < 2; ++it) {
    int idx = it * 512 + tid;          // 0..1023 = (cblk, l)
    int l = idx & 31, cb = idx >> 5;
    int sb = linoff + cb * (8 * LSTR) + l;
    u32 u0 = (u32)lds[sb]            | ((u32)lds[sb + LSTR]     << 16);
    u32 u1 = (u32)lds[sb + 2 * LSTR] | ((u32)lds[sb + 3 * LSTR] << 16);
    u32 u2 = (u32)lds[sb + 4 * LSTR] | ((u32)lds[sb + 5 * LSTR] << 16);
    u32 u3 = (u32)lds[sb + 6 * LSTR] | ((u32)lds[sb + 7 * LSTR] << 16);
    union { u32 u[4]; s8v v; } pw;
    pw.u[0] = u0; pw.u[1] = u1; pw.u[2] = u2; pw.u[3] = u3;
    *reinterpret_cast<s8v*>(&lds[XS + cb * 256 + l * 8]) = pw.v;
  }
}

// q^T / k^T: D[l][o] = sum_c X^T[l][c] W[o][c] + b[o]   (one 32x32 tile, l=32)
__device__ __forceinline__ void proj_T(u16* lds, const u16* __restrict__ w,
                                       const float* __restrict__ bias, int dst,
                                       int wid, int lo, int hi) {
  const int o = wid * 32 + lo;
  f16v a;
#pragma unroll
  for (int i = 0; i < 16; ++i) a[i] = 0.f;
#pragma unroll
  for (int s = 0; s < 16; ++s) {
    const s8v bw = *reinterpret_cast<const s8v*>(w + o * 256 + s * 16 + hi * 8);
    const s8v xf = *reinterpret_cast<const s8v*>(&lds[XS + (2 * s + hi) * 256 + lo * 8]);
    a = __builtin_amdgcn_mfma_f32_32x32x16_bf16(xf, bw, a, 0, 0, 0);
  }
  const float bb = bias[o];
#pragma unroll
  for (int g = 0; g < 4; ++g) {
    uint2 wv2;
    wv2.x = pk2(a[4 * g + 0] + bb, a[4 * g + 1] + bb);
    wv2.y = pk2(a[4 * g + 2] + bb, a[4 * g + 3] + bb);
    // l = 8g + 4hi + i -> lblk = g, j = 4hi..4hi+3
    *reinterpret_cast<uint2*>(&lds[dst + g * 2048 + o * 8 + hi * 4]) = wv2;
  }
}

// v: D[e][l] = sum_c Wv[e][c] X[c][l] + bv[e]
__device__ __forceinline__ void proj_V(u16* lds, const u16* __restrict__ w,
                                       const float* __restrict__ bias,
                                       int wid, int lo, int hi) {
  const int e0 = wid * 32;
  const int e = e0 + lo;
  f16v a;
#pragma unroll
  for (int i = 0; i < 16; ++i) a[i] = 0.f;
#pragma unroll
  for (int s = 0; s < 16; ++s) {
    const s8v aw = *reinterpret_cast<const s8v*>(w + e * 256 + s * 16 + hi * 8);
    const s8v xf = *reinterpret_cast<const s8v*>(&lds[XS + (2 * s + hi) * 256 + lo * 8]);
    a = __builtin_amdgcn_mfma_f32_32x32x16_bf16(aw, xf, a, 0, 0, 0);
  }
#pragma unroll
  for (int g = 0; g < 4; ++g) {
    const int eb = e0 + 8 * g + 4 * hi;
    uint2 wv2;
    wv2.x = pk2(a[4 * g + 0] + bias[eb + 0], a[4 * g + 1] + bias[eb + 1]);
    wv2.y = pk2(a[4 * g + 2] + bias[eb + 2], a[4 * g + 3] + bias[eb + 3]);
    *reinterpret_cast<uint2*>(&lds[VT + (4 * wid + g) * 256 + lo * 8 + hi * 4]) = wv2;
  }
}

// out[o][l] = sum_d Wo[o][d] att[d][l] + bo[o]  (att lives in XS region)
__device__ __forceinline__ void proj_O(u16* lds, const u16* __restrict__ w,
                                       const float* __restrict__ bias,
                                       float* __restrict__ out, long obase,
                                       int wid, int lo, int hi) {
  const int o0 = wid * 32;
  const int o = o0 + lo;
  f16v a;
#pragma unroll
  for (int i = 0; i < 16; ++i) a[i] = 0.f;
#pragma unroll
  for (int s = 0; s < 16; ++s) {
    const s8v aw = *reinterpret_cast<const s8v*>(w + o * 256 + s * 16 + hi * 8);
    const s8v bf = *reinterpret_cast<const s8v*>(&lds[XS + (2 * s + hi) * 256 + lo * 8]);
    a = __builtin_amdgcn_mfma_f32_32x32x16_bf16(aw, bf, a, 0, 0, 0);
  }
#pragma unroll
  for (int r = 0; r < 16; ++r) {
    const int orow = o0 + (r & 3) + 8 * (r >> 2) + 4 * hi;
    out[obase + orow * 16384 + lo] = a[r] + bias[orow];
  }
}

__global__ __launch_bounds__(512)
void mha_kernel(const float* __restrict__ xq, const float* __restrict__ xk,
                const float* __restrict__ xv, const u16* __restrict__ wb,
                const float* __restrict__ bq, const float* __restrict__ bk,
                const float* __restrict__ bv, const float* __restrict__ bo,
                float* __restrict__ out) {
  __shared__ __align__(16) u16 lds[LDS_TOT];  // 67.5 KB -> 2 blocks/CU
  const int tid = threadIdx.x;
  const int lane = tid & 63;
  const int wid = tid >> 6;
  const int lo = lane & 31;
  const int hi = lane >> 5;
  const int hp = blockIdx.x & 1;           // head pair 0 or 1
  const int n = (blockIdx.x >> 1) & 255;
  const int b = blockIdx.x >> 9;
  const long base = (long)b * 4194304 + n * 64 + hp * 32;

  // ---- staged projections; LIN overlays dead regions ----
  stage_lin(xq + base, lds, KT, tid);           // LIN-q @ KT..(+9216)
  __syncthreads();
  lin_to_xs(lds, KT, tid);
  __syncthreads();
  stage_lin(xk + base, lds, KT, tid);           // LIN-k @ KT (free again)
  proj_T(lds, wb + 0, bq, QT, wid, lo, hi);
  __syncthreads();
  lin_to_xs(lds, KT, tid);
  __syncthreads();
  stage_lin(xv + base, lds, VT, tid);           // LIN-v @ VT..(+9216, into pad)
  proj_T(lds, wb + 65536, bk, KT, wid, lo, hi);
  __syncthreads();
  lin_to_xs(lds, VT, tid);
  __syncthreads();
  proj_V(lds, wb + 131072, bv, wid, lo, hi);
  __syncthreads();

  // ---- attention, online softmax over e-tiles; wave owns 32 d-cols ----
  f16v z16;
#pragma unroll
  for (int i = 0; i < 16; ++i) z16[i] = 0.f;
  const int l15 = lane & 15;

#pragma unroll
  for (int h = 0; h < 2; ++h) {
    const s8v qf = *reinterpret_cast<const s8v*>(
        &lds[QT + (2 * h + hi) * 2048 + (wid * 32 + lo) * 8]);
    float m = -3.0e38f, sum = 0.f;
    f16v ot;
#pragma unroll
    for (int i = 0; i < 16; ++i) ot[i] = 0.f;

#pragma unroll
    for (int et = 0; et < 8; ++et) {
      const s8v kf = *reinterpret_cast<const s8v*>(
          &lds[KT + (2 * h + hi) * 2048 + (et * 32 + lo) * 8]);
      f16v st = __builtin_amdgcn_mfma_f32_32x32x16_bf16(kf, qf, z16, 0, 0, 0);

      float tmax = st[0];
#pragma unroll
      for (int i = 1; i < 16; ++i) tmax = fmaxf(tmax, st[i]);
      tmax = fmaxf(tmax, __shfl_xor(tmax, 32));
      const float mn = fmaxf(m, tmax);
      const float f = __expf(0.25f * (m - mn));   // m=-3e38 -> f=0 at first tile
      m = mn;
      sum *= f;
#pragma unroll
      for (int i = 0; i < 16; ++i) ot[i] *= f;
      float ts = 0.f;
#pragma unroll
      for (int i = 0; i < 16; ++i) {
        const float p = __expf(0.25f * (st[i] - m));
        st[i] = p;
        ts += p;
      }
      sum += ts;

      // PV accumulate for this e-tile: e in [32et, 32et+32), 2 k-steps of 16
#pragma unroll
      for (int s2 = 0; s2 < 2; ++s2) {
        const int s = 2 * et + s2;
        const s8v vf = *reinterpret_cast<const s8v*>(
            &lds[VT + (2 * s + hi) * 256 + (h * 16 + l15) * 8]);
        const int q = s2 * 8;
        const u32 x0 = pk2(st[q + 0], st[q + 1]);
        const u32 x1 = pk2(st[q + 2], st[q + 3]);
        const u32 y0 = pk2(st[q + 4], st[q + 5]);
        const u32 y1 = pk2(st[q + 6], st[q + 7]);
        const u32 sx0 = (u32)__shfl_xor((int)x0, 32);
        const u32 sx1 = (u32)__shfl_xor((int)x1, 32);
        const u32 sy0 = (u32)__shfl_xor((int)y0, 32);
        const u32 sy1 = (u32)__shfl_xor((int)y1, 32);
        union { u32 u[4]; s8v v; } bu;
        bu.u[0] = hi ? sy0 : x0;
        bu.u[1] = hi ? sy1 : x1;
        bu.u[2] = hi ? y0 : sx0;
        bu.u[3] = hi ? y1 : sx1;
        ot = __builtin_amdgcn_mfma_f32_32x32x16_bf16(vf, bu.v, ot, 0, 0, 0);
      }
    }
    sum += __shfl_xor(sum, 32);
    const float rinv = 1.0f / sum;
    // store O^T rows 0..15 into ATT (@XS): [dblk][l][j]
#pragma unroll
    for (int r = 0; r < 8; ++r) {
      const int lh = (r & 3) + 8 * (r >> 2) + 4 * hi;   // 0..15
      const int l = h * 16 + lh;
      const int d = wid * 32 + lo;
      lds[XS + (d >> 3) * 256 + l * 8 + (d & 7)] = f2bf(ot[r] * rinv);
    }
  }
  __syncthreads();

  proj_O(lds, wb + 196608, bo, out, base, wid, lo, hi);
}

extern "C" void kernel_launch(void* const* d_in, const int* in_sizes, int n_in,
                              void* d_out, int out_size, void* d_ws, size_t ws_size,
                              hipStream_t stream) {
  const float* xq = (const float*)d_in[0];
  const float* xk = (const float*)d_in[1];
  const float* xv = (const float*)d_in[2];
  const float* wq = (const float*)d_in[3];
  const float* bq = (const float*)d_in[4];
  const float* wk = (const float*)d_in[5];
  const float* bk = (const float*)d_in[6];
  const float* wv = (const float*)d_in[7];
  const float* bv = (const float*)d_in[8];
  const float* wo = (const float*)d_in[9];
  const float* bo = (const float*)d_in[10];
  u16* wsb = (u16*)d_ws;  // 4 * 65536 bf16 = 512 KB
  float* out = (float*)d_out;

  cvt_weights<<<dim3(256), dim3(256), 0, stream>>>(wq, wk, wv, wo, wsb);
  mha_kernel<<<dim3(2048), dim3(512), 0, stream>>>(xq, xk, xv, wsb, bq, bk, bv, bo, out);
}